// Round 7
// baseline (1553.817 us; speedup 1.0000x reference)
//
#include <hip/hip_runtime.h>
#include <hip/hip_bf16.h>
#include <math.h>

#define B 256
#define S 128
#define I_DIM 512
#define H 1024
#define C 10
#define WROW 1536

#define LDS_H 131072                 // 64 b-rows x 1024 k bf16, XOR-swizzled

typedef float f32x4 __attribute__((ext_vector_type(4), may_alias));
typedef __bf16 bf16x8 __attribute__((ext_vector_type(8), may_alias));
typedef unsigned int u32x4 __attribute__((ext_vector_type(4), may_alias));
typedef unsigned long long u64;
typedef unsigned long long __attribute__((may_alias)) u64a;

__device__ __forceinline__ unsigned short f2bf(float f) {
    union { float f; unsigned u; } a; a.f = f;
    return (unsigned short)((a.u + 0x7fffu + ((a.u >> 16) & 1u)) >> 16);
}
__device__ __forceinline__ float sigf(float v) { return 1.0f / (1.0f + __expf(-v)); }
__device__ __forceinline__ float tanh_fast(float v) { return 1.0f - 2.0f / (1.0f + __expf(2.0f * v)); }

// ---- prep 1: W recurrent part -> bf16 in exact MFMA-fragment stream order ----
// wF[(((d*256+nsub)*32+kk)*64+lane)*8 + e] = W_d[g*1024+j][512 + kk*32 + (lane>>4)*8 + e]
//   where n_gl = nsub*16 + (lane&15), j = n_gl>>2, g = n_gl&3
__global__ void wf_build(const float* __restrict__ fwd_W,
                         const float* __restrict__ bwd_W,
                         __hip_bfloat16* __restrict__ wF) {
    int gid = blockIdx.x * 256 + threadIdx.x;   // 2*256*32*64 = 1,048,576
    int lane = gid & 63, kk = (gid >> 6) & 31, nsub = (gid >> 11) & 255, d = gid >> 19;
    int n_gl = nsub * 16 + (lane & 15);
    int j = n_gl >> 2, g = n_gl & 3;
    int k = kk * 32 + (lane >> 4) * 8;
    const float* W = d ? bwd_W : fwd_W;
    const float* src = W + (size_t)(g * 1024 + j) * WROW + I_DIM + k;
    ushort4 lo = make_ushort4(f2bf(src[0]), f2bf(src[1]), f2bf(src[2]), f2bf(src[3]));
    ushort4 hi = make_ushort4(f2bf(src[4]), f2bf(src[5]), f2bf(src[6]), f2bf(src[7]));
    ushort4* dst = (ushort4*)(wF + (size_t)gid * 8);
    dst[0] = lo; dst[1] = hi;
}

// ---- prep 2: projP[d][j][v][g] (f32), vectorized: 512 blocks x 256 thr ----
// block = (d, nc): 16 n-rows; thread = (r = tid&15, vg = tid>>4): 8 v per thread.
__global__ void projp_kernel(const float* __restrict__ embed,
                             const float* __restrict__ fwd_W,
                             const float* __restrict__ fwd_b,
                             const float* __restrict__ bwd_W,
                             const float* __restrict__ bwd_b,
                             float* __restrict__ projP) {
    __shared__ float wrows[16][520];
    int d  = blockIdx.x >> 8;
    int nc = blockIdx.x & 255;
    int n0 = nc * 16;
    const float* W    = d ? bwd_W : fwd_W;
    const float* bias = d ? bwd_b : fwd_b;
    int tid = threadIdx.x;
    for (int i = tid; i < 16 * 128; i += 256) {
        int r = i >> 7, kc = i & 127;
        *(f32x4*)&wrows[r][kc * 4] = *(const f32x4*)(W + (size_t)(n0 + r) * WROW + kc * 4);
    }
    __syncthreads();
    const int r = tid & 15, vg = tid >> 4;
    const float* eb = embed + (size_t)(vg * 8) * I_DIM;
    f32x4 acc[8] = {};
    for (int kc = 0; kc < 128; kc++) {
        f32x4 w = *(const f32x4*)&wrows[r][kc * 4];
#pragma unroll
        for (int vi = 0; vi < 8; vi++) {
            f32x4 e = *(const f32x4*)(eb + (size_t)vi * I_DIM + kc * 4);
            acc[vi] += w * e;
        }
    }
    const int n = n0 + r, g = n >> 10, j = n & 1023;
    const float bv = bias[n];
    float* outp = projP + ((size_t)d * 1024 + j) * 128 * 4 + g;
#pragma unroll
    for (int vi = 0; vi < 8; vi++) {
        float s = acc[vi][0] + acc[vi][1] + acc[vi][2] + acc[vi][3] + bv;
        outp[(vg * 8 + vi) * 4] = s;
    }
}

// ---- fused per-step kernel ----
// 256 blocks x 512 thr. XCD-grouped swizzle: all 4 bt-duplicates of (d,jt) share
// an XCD so their 256 KB wF slice stays L2-hot. block=(d,bt,jt): 64 b x 32 j.
// 8 waves: wave wid owns j = jt*32 + wid*4 + l4 (16 n) x 64 b.
// A = W-frag streamed from wF (8-deep ring prefetch), B = h-frag from swizzled LDS.
// C layout (HW-verified): col(l15)=b, row(l4*4+reg): j-sub=l4, gate=reg.
__global__ __launch_bounds__(512, 1) void step_kernel(
        const int* __restrict__ x,
        const __hip_bfloat16* __restrict__ wF,
        const float* __restrict__ projP,
        __hip_bfloat16* __restrict__ hbuf,   // [2 parity][2 d][256 b][1024 j]
        float* __restrict__ cws,             // [256 blk][512 tid][4]
        int t) {
    extern __shared__ char smem[];
    const int bid = blockIdx.x;
    // XCD-group swizzle (perf heuristic only; bijective 256->256)
    const int xcd = bid & 7, idx = bid >> 3;         // idx 0..31
    const int slot = idx >> 2, bt = idx & 3;         // slot 0..7
    const int grp = slot * 8 + xcd;                  // 0..63
    const int d = grp >> 5, jt = grp & 31;
    const int tid = threadIdx.x, wid = tid >> 6, lane = tid & 63;
    const int l15 = lane & 15, l4 = lane >> 4;
    const int b0 = bt * 64;
    const size_t dBH = (size_t)d * B * H;

    const __hip_bfloat16* wp = wF + (size_t)(d * 256 + jt * 8 + wid) * 16384;

    // ---- issue all long-latency loads first (overlap with staging) ----
    bf16x8 Ap[8];
    if (t > 0) {
#pragma unroll
        for (int p = 0; p < 8; p++)
            Ap[p] = *(const bf16x8*)(wp + p * 512 + lane * 8);
    }
    const int tt = d ? (S - 1 - t) : t;
    int vv[4];
#pragma unroll
    for (int bs = 0; bs < 4; bs++)
        vv[bs] = x[(b0 + bs * 16 + l15) * S + tt];

    float* cp = cws + ((size_t)bid * 512 + tid) * 4;
    f32x4 cv = {0.f, 0.f, 0.f, 0.f};
    if (t > 0) cv = *(const f32x4*)cp;

    // stage h[d][b0..b0+64][*] into LDS (bf16, XOR-swizzled rows)
    if (t > 0) {
        const __hip_bfloat16* hr = hbuf + (size_t)(t & 1) * 2 * B * H + dBH + (size_t)b0 * H;
#pragma unroll
        for (int i = 0; i < 16; i++) {
            int flat = i * 512 + tid;        // row = flat>>7, c16 = flat&127
            int row = flat >> 7, c16 = flat & 127;
            u32x4 v = *(const u32x4*)(hr + (size_t)row * H + c16 * 8);
            *(u32x4*)(smem + row * 2048 + ((c16 * 16) ^ ((row & 7) << 4))) = v;
        }
    }

    // proj gather (x values have arrived by now)
    const int j = jt * 32 + wid * 4 + l4;
    const f32x4* pp = (const f32x4*)projP + ((size_t)d * 1024 + j) * 128;
    f32x4 pj[4];
#pragma unroll
    for (int bs = 0; bs < 4; bs++) pj[bs] = pp[vv[bs]];

    f32x4 acc[4] = {};
    if (t > 0) {
        __syncthreads();
        int brow[4], bswz[4];
#pragma unroll
        for (int bs = 0; bs < 4; bs++) {
            int row = bs * 16 + l15;
            brow[bs] = row * 2048;
            bswz[bs] = (row & 7) << 4;
        }
        bf16x8 Bcur[4];
#pragma unroll
        for (int bs = 0; bs < 4; bs++)
            Bcur[bs] = *(const bf16x8*)(smem + brow[bs] + ((l4 * 16) ^ bswz[bs]));
#pragma unroll
        for (int kk = 0; kk < 32; kk++) {
            bf16x8 A = Ap[kk & 7];
            if (kk < 24)
                Ap[kk & 7] = *(const bf16x8*)(wp + (kk + 8) * 512 + lane * 8);
            bf16x8 B0 = Bcur[0], B1 = Bcur[1], B2 = Bcur[2], B3 = Bcur[3];
            if (kk < 31) {
                int koff = (kk + 1) * 64 + l4 * 16;
#pragma unroll
                for (int bs = 0; bs < 4; bs++)
                    Bcur[bs] = *(const bf16x8*)(smem + brow[bs] + (koff ^ bswz[bs]));
            }
            acc[0] = __builtin_amdgcn_mfma_f32_16x16x32_bf16(A, B0, acc[0], 0, 0, 0);
            acc[1] = __builtin_amdgcn_mfma_f32_16x16x32_bf16(A, B1, acc[1], 0, 0, 0);
            acc[2] = __builtin_amdgcn_mfma_f32_16x16x32_bf16(A, B2, acc[2], 0, 0, 0);
            acc[3] = __builtin_amdgcn_mfma_f32_16x16x32_bf16(A, B3, acc[3], 0, 0, 0);
        }
    }

    float hnv[4];
#pragma unroll
    for (int bs = 0; bs < 4; bs++) {
        float zg = acc[bs][0] + pj[bs][0];
        float zi = acc[bs][1] + pj[bs][1];
        float zf = acc[bs][2] + pj[bs][2];
        float zo = acc[bs][3] + pj[bs][3];
        float gg = tanh_fast(zg);
        float ii = sigf(zi);
        float ff = sigf(zf);
        float oo = sigf(zo);
        float cn = gg * ii + cv[bs] * ff;
        cv[bs] = cn;
        hnv[bs] = tanh_fast(cn) * oo;
    }
    *(f32x4*)cp = cv;

    // pure-register wave transpose via shfl (no LDS, no aliasing hazard):
    // writer lane w holds h[b0 + bs*16 + (w&15)][j0 + (w>>4)] in hnv[bs];
    // reader lane l needs h[b0 + l][j0 + p], p=0..3 -> from lane p*16 + (l&15),
    // sub-word bs = l>>4.
    unsigned plo = (unsigned)f2bf(hnv[0]) | ((unsigned)f2bf(hnv[1]) << 16);
    unsigned phi = (unsigned)f2bf(hnv[2]) | ((unsigned)f2bf(hnv[3]) << 16);
    unsigned short o4[4];
#pragma unroll
    for (int p = 0; p < 4; p++) {
        int src = p * 16 + l15;
        unsigned vlo = __shfl(plo, src);
        unsigned vhi = __shfl(phi, src);
        unsigned sel = (l4 < 2) ? vlo : vhi;
        o4[p] = (l4 & 1) ? (unsigned short)(sel >> 16) : (unsigned short)(sel & 0xffffu);
    }
    u64 hv = (u64)o4[0] | ((u64)o4[1] << 16) | ((u64)o4[2] << 32) | ((u64)o4[3] << 48);
    __hip_bfloat16* hw = hbuf + (size_t)((t + 1) & 1) * 2 * B * H + dBH
                         + (size_t)(b0 + lane) * H + jt * 32 + wid * 4;
    *(u64a*)hw = hv;
}

// ---- head: logits + log_softmax (reads bf16 h, parity 0) ----
__global__ void head_kernel(const __hip_bfloat16* __restrict__ hbuf,
                            const float* __restrict__ p_w,
                            const float* __restrict__ p_b,
                            float* __restrict__ out) {
    int b = blockIdx.x;
    int lane = threadIdx.x;  // 64
    float part[C];
#pragma unroll
    for (int cc = 0; cc < C; cc++) part[cc] = 0.0f;
    for (int jj = lane; jj < 2 * H; jj += 64) {
        float hv = (jj < H)
            ? __bfloat162float(hbuf[(size_t)b * H + jj])
            : __bfloat162float(hbuf[(size_t)B * H + (size_t)b * H + jj - H]);
#pragma unroll
        for (int cc = 0; cc < C; cc++) part[cc] += hv * p_w[cc * 2 * H + jj];
    }
#pragma unroll
    for (int cc = 0; cc < C; cc++) {
        float v = part[cc];
        for (int off = 32; off; off >>= 1) v += __shfl_down(v, off);
        part[cc] = v;
    }
    if (lane == 0) {
        float lg[C];
        float m = -1e30f;
        for (int cc = 0; cc < C; cc++) {
            lg[cc] = part[cc] + p_b[cc];
            m = fmaxf(m, lg[cc]);
        }
        float s = 0.0f;
        for (int cc = 0; cc < C; cc++) s += expf(lg[cc] - m);
        float lse = logf(s) + m;
        for (int cc = 0; cc < C; cc++) out[b * C + cc] = lg[cc] - lse;
    }
}

extern "C" void kernel_launch(void* const* d_in, const int* in_sizes, int n_in,
                              void* d_out, int out_size, void* d_ws, size_t ws_size,
                              hipStream_t stream) {
    const int*   x     = (const int*)d_in[0];
    const float* embed = (const float*)d_in[1];
    const float* fwd_W = (const float*)d_in[2];
    const float* fwd_b = (const float*)d_in[3];
    const float* bwd_W = (const float*)d_in[4];
    const float* bwd_b = (const float*)d_in[5];
    const float* p_w   = (const float*)d_in[6];
    const float* p_b   = (const float*)d_in[7];
    float* outp = (float*)d_out;

    char* ws = (char*)d_ws;
    __hip_bfloat16* wF = (__hip_bfloat16*)ws;  ws += (size_t)2 * 256 * 16384 * 2;     // 16 MB
    float* projP = (float*)ws;                 ws += (size_t)2 * 1024 * 128 * 4 * 4;  // 4 MB
    __hip_bfloat16* hbuf = (__hip_bfloat16*)ws; ws += (size_t)2 * 2 * B * H * 2;      // 2 MB
    float* cws = (float*)ws;                   ws += (size_t)256 * 512 * 4 * 4;       // 2 MB

    hipLaunchKernelGGL(wf_build, dim3(4096), dim3(256), 0, stream, fwd_W, bwd_W, wF);
    hipLaunchKernelGGL(projp_kernel, dim3(512), dim3(256), 0, stream,
                       embed, fwd_W, fwd_b, bwd_W, bwd_b, projP);

    hipFuncSetAttribute((const void*)step_kernel,
                        hipFuncAttributeMaxDynamicSharedMemorySize, LDS_H);

    for (int t = 0; t < S; t++)
        hipLaunchKernelGGL(step_kernel, dim3(256), dim3(512), LDS_H, stream,
                           x, wF, projP, hbuf, cws, t);

    hipLaunchKernelGGL(head_kernel, dim3(B), dim3(64), 0, stream,
                       hbuf, p_w, p_b, outp);
}

// Round 8
// 1545.682 us; speedup vs baseline: 1.0053x; 1.0053x over previous
//
#include <hip/hip_runtime.h>
#include <hip/hip_bf16.h>
#include <math.h>

#define B 256
#define S 128
#define I_DIM 512
#define H 1024
#define C 10
#define WROW 1536

#define LDS_H 131072                 // 64 b-rows x 1024 k bf16, XOR-swizzled

typedef float f32x4 __attribute__((ext_vector_type(4), may_alias));
typedef __bf16 bf16x8 __attribute__((ext_vector_type(8), may_alias));
typedef unsigned int u32x4 __attribute__((ext_vector_type(4), may_alias));
typedef unsigned long long u64;

__device__ __forceinline__ unsigned short f2bf(float f) {
    union { float f; unsigned u; } a; a.f = f;
    return (unsigned short)((a.u + 0x7fffu + ((a.u >> 16) & 1u)) >> 16);
}
__device__ __forceinline__ float sigf(float v) { return 1.0f / (1.0f + __expf(-v)); }
__device__ __forceinline__ float tanh_fast(float v) { return 1.0f - 2.0f / (1.0f + __expf(2.0f * v)); }

// ---- prep 1: W recurrent part -> bf16 in exact MFMA-fragment stream order ----
__global__ void wf_build(const float* __restrict__ fwd_W,
                         const float* __restrict__ bwd_W,
                         __hip_bfloat16* __restrict__ wF) {
    int gid = blockIdx.x * 256 + threadIdx.x;   // 2*256*32*64
    int lane = gid & 63, kk = (gid >> 6) & 31, nsub = (gid >> 11) & 255, d = gid >> 19;
    int n_gl = nsub * 16 + (lane & 15);
    int j = n_gl >> 2, g = n_gl & 3;
    int k = kk * 32 + (lane >> 4) * 8;
    const float* W = d ? bwd_W : fwd_W;
    const float* src = W + (size_t)(g * 1024 + j) * WROW + I_DIM + k;
    ushort4 lo = make_ushort4(f2bf(src[0]), f2bf(src[1]), f2bf(src[2]), f2bf(src[3]));
    ushort4 hi = make_ushort4(f2bf(src[4]), f2bf(src[5]), f2bf(src[6]), f2bf(src[7]));
    ushort4* dst = (ushort4*)(wF + (size_t)gid * 8);
    dst[0] = lo; dst[1] = hi;
}

// ---- prep 2: projP[d][j][v][g] (f32) vectorized; conflict-free stride 516 ----
__global__ void projp_kernel(const float* __restrict__ embed,
                             const float* __restrict__ fwd_W,
                             const float* __restrict__ fwd_b,
                             const float* __restrict__ bwd_W,
                             const float* __restrict__ bwd_b,
                             float* __restrict__ projP) {
    __shared__ float wrows[16][516];   // 516 % 32 == 4 -> 2-way max on f32x4 reads
    int d  = blockIdx.x >> 8;
    int nc = blockIdx.x & 255;
    int n0 = nc * 16;
    const float* W    = d ? bwd_W : fwd_W;
    const float* bias = d ? bwd_b : fwd_b;
    int tid = threadIdx.x;
    for (int i = tid; i < 16 * 128; i += 256) {
        int r = i >> 7, kc = i & 127;
        *(f32x4*)&wrows[r][kc * 4] = *(const f32x4*)(W + (size_t)(n0 + r) * WROW + kc * 4);
    }
    __syncthreads();
    const int r = tid & 15, vg = tid >> 4;
    const float* eb = embed + (size_t)(vg * 8) * I_DIM;
    f32x4 acc[8] = {};
    for (int kc = 0; kc < 128; kc++) {
        f32x4 w = *(const f32x4*)&wrows[r][kc * 4];
#pragma unroll
        for (int vi = 0; vi < 8; vi++) {
            f32x4 e = *(const f32x4*)(eb + (size_t)vi * I_DIM + kc * 4);
            acc[vi] += w * e;
        }
    }
    const int n = n0 + r, g = n >> 10, j = n & 1023;
    const float bv = bias[n];
    float* outp = projP + ((size_t)d * 1024 + j) * 128 * 4 + g;
#pragma unroll
    for (int vi = 0; vi < 8; vi++) {
        float s = acc[vi][0] + acc[vi][1] + acc[vi][2] + acc[vi][3] + bv;
        outp[(vg * 8 + vi) * 4] = s;
    }
}

// stage 8 x 16B chunks of h from global (L3-coherent sc0 sc1) into swizzled LDS
__device__ __forceinline__ void stage8(const __hip_bfloat16* hr, int r0, int cc,
                                       char* smem, int ibase) {
    const void* p0 = (const void*)(hr + (size_t)((ibase + 0) * 4 + r0) * H + cc * 8);
    const void* p1 = (const void*)(hr + (size_t)((ibase + 1) * 4 + r0) * H + cc * 8);
    const void* p2 = (const void*)(hr + (size_t)((ibase + 2) * 4 + r0) * H + cc * 8);
    const void* p3 = (const void*)(hr + (size_t)((ibase + 3) * 4 + r0) * H + cc * 8);
    const void* p4 = (const void*)(hr + (size_t)((ibase + 4) * 4 + r0) * H + cc * 8);
    const void* p5 = (const void*)(hr + (size_t)((ibase + 5) * 4 + r0) * H + cc * 8);
    const void* p6 = (const void*)(hr + (size_t)((ibase + 6) * 4 + r0) * H + cc * 8);
    const void* p7 = (const void*)(hr + (size_t)((ibase + 7) * 4 + r0) * H + cc * 8);
    u32x4 s0, s1, s2, s3, s4, s5, s6, s7;
    asm volatile(
        "global_load_dwordx4 %0, %8, off sc0 sc1\n\t"
        "global_load_dwordx4 %1, %9, off sc0 sc1\n\t"
        "global_load_dwordx4 %2, %10, off sc0 sc1\n\t"
        "global_load_dwordx4 %3, %11, off sc0 sc1\n\t"
        "global_load_dwordx4 %4, %12, off sc0 sc1\n\t"
        "global_load_dwordx4 %5, %13, off sc0 sc1\n\t"
        "global_load_dwordx4 %6, %14, off sc0 sc1\n\t"
        "global_load_dwordx4 %7, %15, off sc0 sc1\n\t"
        "s_waitcnt vmcnt(0)"
        : "=&v"(s0), "=&v"(s1), "=&v"(s2), "=&v"(s3),
          "=&v"(s4), "=&v"(s5), "=&v"(s6), "=&v"(s7)
        : "v"(p0), "v"(p1), "v"(p2), "v"(p3), "v"(p4), "v"(p5), "v"(p6), "v"(p7)
        : "memory");
    int row;
    row = (ibase + 0) * 4 + r0; *(u32x4*)(smem + row * 2048 + ((cc * 16) ^ ((row & 7) << 4))) = s0;
    row = (ibase + 1) * 4 + r0; *(u32x4*)(smem + row * 2048 + ((cc * 16) ^ ((row & 7) << 4))) = s1;
    row = (ibase + 2) * 4 + r0; *(u32x4*)(smem + row * 2048 + ((cc * 16) ^ ((row & 7) << 4))) = s2;
    row = (ibase + 3) * 4 + r0; *(u32x4*)(smem + row * 2048 + ((cc * 16) ^ ((row & 7) << 4))) = s3;
    row = (ibase + 4) * 4 + r0; *(u32x4*)(smem + row * 2048 + ((cc * 16) ^ ((row & 7) << 4))) = s4;
    row = (ibase + 5) * 4 + r0; *(u32x4*)(smem + row * 2048 + ((cc * 16) ^ ((row & 7) << 4))) = s5;
    row = (ibase + 6) * 4 + r0; *(u32x4*)(smem + row * 2048 + ((cc * 16) ^ ((row & 7) << 4))) = s6;
    row = (ibase + 7) * 4 + r0; *(u32x4*)(smem + row * 2048 + ((cc * 16) ^ ((row & 7) << 4))) = s7;
}

// ---- persistent bi-LSTM, all 128 steps in one dispatch ----
// 256 blocks x 512 thr, 1 block/CU. bid -> (d, jt, bt) with (d, jt-octet) per XCD
// so each XCD's 2 MB weight slice stays L2-resident. h exchanged through L3 via
// sc0|sc1 plain vector ops (no fences, no cache maintenance, mapping-independent).
// Sync: per-(d,bt) group of 32 blocks, relaxed atomic flag + poll.
__global__ __launch_bounds__(512, 2) void bilstm_persistent(
        const int* __restrict__ x,
        const __hip_bfloat16* __restrict__ wF,
        const float* __restrict__ projP,
        __hip_bfloat16* __restrict__ hbuf,   // [2 parity][2 d][256 b][1024 j]
        unsigned* __restrict__ flags) {      // [S][8] slots, stride 16 u32
    extern __shared__ char smem[];
    const int bid = blockIdx.x;
    const int xcd = bid & 7;
    const int d = xcd >> 2, jtHi = xcd & 3;
    const int idx = bid >> 3;
    const int jtLo = idx >> 2, bt = idx & 3;
    const int jt = jtHi * 8 + jtLo;
    const int tid = threadIdx.x, wid = tid >> 6, lane = tid & 63;
    const int l15 = lane & 15, l4 = lane >> 4;
    const int b0 = bt * 64;
    const size_t dBH = (size_t)d * B * H;

    const __hip_bfloat16* wp = wF + (size_t)(d * 256 + jt * 8 + wid) * 16384;
    const int j = jt * 32 + wid * 4 + l4;
    const f32x4* pp = (const f32x4*)projP + ((size_t)d * 1024 + j) * 128;
    const int r0 = tid >> 7;          // staging row group 0..3
    const int cc = tid & 127;         // staging 16B-chunk col

    int brow[4], bswz[4];
#pragma unroll
    for (int bs = 0; bs < 4; bs++) {
        int row = bs * 16 + l15;
        brow[bs] = row * 2048;
        bswz[bs] = (row & 7) << 4;
    }

    float cst[4] = {0.f, 0.f, 0.f, 0.f};

    for (int t = 0; t < S; t++) {
        // wait for previous step's h (own (d,bt) group, 32 blocks)
        if (t > 0) {
            if (tid == 0) {
                const unsigned* p = flags + (size_t)((t - 1) * 8 + d * 4 + bt) * 16;
                while (__hip_atomic_load(p, __ATOMIC_RELAXED, __HIP_MEMORY_SCOPE_AGENT) < 32u)
                    __builtin_amdgcn_s_sleep(4);
            }
            __syncthreads();
        }

        // issue weight-ring preload (L2-hot) and x gather early
        bf16x8 Ap[8];
        if (t > 0) {
#pragma unroll
            for (int p = 0; p < 8; p++)
                Ap[p] = *(const bf16x8*)(wp + p * 512 + lane * 8);
        }
        const int tt = d ? (S - 1 - t) : t;
        int vv[4];
#pragma unroll
        for (int bs = 0; bs < 4; bs++)
            vv[bs] = x[(b0 + bs * 16 + l15) * S + tt];

        // stage h into LDS (coherent sc0|sc1 loads), then barrier
        if (t > 0) {
            const __hip_bfloat16* hr = hbuf + (size_t)(t & 1) * 2 * B * H + dBH + (size_t)b0 * H;
            stage8(hr, r0, cc, smem, 0);
            stage8(hr, r0, cc, smem, 8);
        }

        f32x4 pj[4];
#pragma unroll
        for (int bs = 0; bs < 4; bs++) pj[bs] = pp[vv[bs]];

        f32x4 acc[4] = {};
        if (t > 0) {
            __syncthreads();
            bf16x8 Bcur[4];
#pragma unroll
            for (int bs = 0; bs < 4; bs++)
                Bcur[bs] = *(const bf16x8*)(smem + brow[bs] + ((l4 * 16) ^ bswz[bs]));
#pragma unroll
            for (int kk = 0; kk < 32; kk++) {
                bf16x8 A = Ap[kk & 7];
                if (kk < 24)
                    Ap[kk & 7] = *(const bf16x8*)(wp + (kk + 8) * 512 + lane * 8);
                bf16x8 B0 = Bcur[0], B1 = Bcur[1], B2 = Bcur[2], B3 = Bcur[3];
                if (kk < 31) {
                    int koff = (kk + 1) * 64 + l4 * 16;
#pragma unroll
                    for (int bs = 0; bs < 4; bs++)
                        Bcur[bs] = *(const bf16x8*)(smem + brow[bs] + (koff ^ bswz[bs]));
                }
                acc[0] = __builtin_amdgcn_mfma_f32_16x16x32_bf16(A, B0, acc[0], 0, 0, 0);
                acc[1] = __builtin_amdgcn_mfma_f32_16x16x32_bf16(A, B1, acc[1], 0, 0, 0);
                acc[2] = __builtin_amdgcn_mfma_f32_16x16x32_bf16(A, B2, acc[2], 0, 0, 0);
                acc[3] = __builtin_amdgcn_mfma_f32_16x16x32_bf16(A, B3, acc[3], 0, 0, 0);
            }
        }

        // gates; c stays in registers across all steps
        float hnv[4];
#pragma unroll
        for (int bs = 0; bs < 4; bs++) {
            float zg = acc[bs][0] + pj[bs][0];
            float zi = acc[bs][1] + pj[bs][1];
            float zf = acc[bs][2] + pj[bs][2];
            float zo = acc[bs][3] + pj[bs][3];
            float gg = tanh_fast(zg);
            float ii = sigf(zi);
            float ff = sigf(zf);
            float oo = sigf(zo);
            float cn = gg * ii + cst[bs] * ff;
            cst[bs] = cn;
            hnv[bs] = tanh_fast(cn) * oo;
        }

        // register shfl transpose -> coherent 8B store (sc0|sc1, through to L3)
        unsigned plo = (unsigned)f2bf(hnv[0]) | ((unsigned)f2bf(hnv[1]) << 16);
        unsigned phi = (unsigned)f2bf(hnv[2]) | ((unsigned)f2bf(hnv[3]) << 16);
        unsigned short o4[4];
#pragma unroll
        for (int p = 0; p < 4; p++) {
            int src = p * 16 + l15;
            unsigned vlo = __shfl(plo, src);
            unsigned vhi = __shfl(phi, src);
            unsigned sel = (l4 < 2) ? vlo : vhi;
            o4[p] = (l4 & 1) ? (unsigned short)(sel >> 16) : (unsigned short)(sel & 0xffffu);
        }
        u64 hv = (u64)o4[0] | ((u64)o4[1] << 16) | ((u64)o4[2] << 32) | ((u64)o4[3] << 48);
        void* hw = (void*)(hbuf + (size_t)((t + 1) & 1) * 2 * B * H + dBH
                           + (size_t)(b0 + lane) * H + jt * 32 + wid * 4);
        asm volatile("global_store_dwordx2 %0, %1, off sc0 sc1"
                     :: "v"(hw), "v"(hv) : "memory");

        // drain (syncthreads emits vmcnt(0) per wave) then signal
        __syncthreads();
        if (tid == 0)
            __hip_atomic_fetch_add(flags + (size_t)(t * 8 + d * 4 + bt) * 16, 1u,
                                   __ATOMIC_RELAXED, __HIP_MEMORY_SCOPE_AGENT);
    }
}

// ---- head: logits + log_softmax (reads bf16 h, parity 0) ----
__global__ void head_kernel(const __hip_bfloat16* __restrict__ hbuf,
                            const float* __restrict__ p_w,
                            const float* __restrict__ p_b,
                            float* __restrict__ out) {
    int b = blockIdx.x;
    int lane = threadIdx.x;  // 64
    float part[C];
#pragma unroll
    for (int cc = 0; cc < C; cc++) part[cc] = 0.0f;
    for (int jj = lane; jj < 2 * H; jj += 64) {
        float hv = (jj < H)
            ? __bfloat162float(hbuf[(size_t)b * H + jj])
            : __bfloat162float(hbuf[(size_t)B * H + (size_t)b * H + jj - H]);
#pragma unroll
        for (int cc = 0; cc < C; cc++) part[cc] += hv * p_w[cc * 2 * H + jj];
    }
#pragma unroll
    for (int cc = 0; cc < C; cc++) {
        float v = part[cc];
        for (int off = 32; off; off >>= 1) v += __shfl_down(v, off);
        part[cc] = v;
    }
    if (lane == 0) {
        float lg[C];
        float m = -1e30f;
        for (int cc = 0; cc < C; cc++) {
            lg[cc] = part[cc] + p_b[cc];
            m = fmaxf(m, lg[cc]);
        }
        float s = 0.0f;
        for (int cc = 0; cc < C; cc++) s += expf(lg[cc] - m);
        float lse = logf(s) + m;
        for (int cc = 0; cc < C; cc++) out[b * C + cc] = lg[cc] - lse;
    }
}

extern "C" void kernel_launch(void* const* d_in, const int* in_sizes, int n_in,
                              void* d_out, int out_size, void* d_ws, size_t ws_size,
                              hipStream_t stream) {
    const int*   x     = (const int*)d_in[0];
    const float* embed = (const float*)d_in[1];
    const float* fwd_W = (const float*)d_in[2];
    const float* fwd_b = (const float*)d_in[3];
    const float* bwd_W = (const float*)d_in[4];
    const float* bwd_b = (const float*)d_in[5];
    const float* p_w   = (const float*)d_in[6];
    const float* p_b   = (const float*)d_in[7];
    float* outp = (float*)d_out;

    char* ws = (char*)d_ws;
    __hip_bfloat16* wF = (__hip_bfloat16*)ws;  ws += (size_t)2 * 256 * 16384 * 2;     // 16 MB
    float* projP = (float*)ws;                 ws += (size_t)2 * 1024 * 128 * 4 * 4;  // 4 MB
    __hip_bfloat16* hbuf = (__hip_bfloat16*)ws; ws += (size_t)2 * 2 * B * H * 2;      // 2 MB
    unsigned* flags = (unsigned*)ws;           ws += (size_t)S * 8 * 16 * 4;          // 64 KB

    hipMemsetAsync(flags, 0, (size_t)S * 8 * 16 * 4, stream);
    hipLaunchKernelGGL(wf_build, dim3(4096), dim3(256), 0, stream, fwd_W, bwd_W, wF);
    hipLaunchKernelGGL(projp_kernel, dim3(512), dim3(256), 0, stream,
                       embed, fwd_W, fwd_b, bwd_W, bwd_b, projP);

    hipFuncSetAttribute((const void*)bilstm_persistent,
                        hipFuncAttributeMaxDynamicSharedMemorySize, LDS_H);

    void* args[] = {(void*)&x, (void*)&wF, (void*)&projP, (void*)&hbuf, (void*)&flags};
    hipLaunchCooperativeKernel((void*)bilstm_persistent, dim3(256), dim3(512),
                               args, LDS_H, stream);

    hipLaunchKernelGGL(head_kernel, dim3(B), dim3(64), 0, stream,
                       hbuf, p_w, p_b, outp);
}